// Round 1
// baseline (403.711 us; speedup 1.0000x reference)
//
#include <hip/hip_runtime.h>
#include <hip/hip_bf16.h>
#include <cstddef>

#define L_ 768
#define CS_ 384
#define CZ_ 128
#define CH_ 32
#define H_ 12
#define LL_ (L_*L_)
#define EPS_ 1e-5f

// ---------------- prep: fold LN(z) affine into w_z ----------------
// ww[h][c] = ln_z_w[c] * w_z[h][c];  sumww[h] = sum_c ww;  bb[h] = sum_c ln_z_b[c]*w_z[h][c]
__global__ void prep_kernel(const float* __restrict__ lnzw, const float* __restrict__ lnzb,
                            const float* __restrict__ wz,
                            float* __restrict__ ww, float* __restrict__ sumww,
                            float* __restrict__ bb) {
    int h = threadIdx.x;
    if (h < H_) {
        float sw = 0.f, sb = 0.f;
        for (int c = 0; c < CZ_; ++c) {
            float wv = lnzw[c] * wz[h*CZ_ + c];
            ww[h*CZ_ + c] = wv;
            sw += wv;
            sb += lnzb[c] * wz[h*CZ_ + c];
        }
        sumww[h] = sw;
        bb[h] = sb;
    }
}

// ---------------- bias: fused LN(z) + pair-bias projection ----------------
// one lane per (i,j) pair; streams the 512B z row once; 14 accumulators.
__global__ __launch_bounds__(256) void bias_kernel(const float* __restrict__ z,
        const float* __restrict__ ww, const float* __restrict__ sumww,
        const float* __restrict__ bb, float* __restrict__ bias) {
    int p = blockIdx.x * 256 + threadIdx.x;        // pair index 0..589823
    const float4* zr = (const float4*)(z + (size_t)p * CZ_);
    float acc[H_];
    #pragma unroll
    for (int h = 0; h < H_; ++h) acc[h] = 0.f;
    float s = 0.f, s2 = 0.f;
    for (int c4 = 0; c4 < CZ_/4; ++c4) {
        float4 zv = zr[c4];
        float ze[4] = {zv.x, zv.y, zv.z, zv.w};
        #pragma unroll
        for (int e = 0; e < 4; ++e) {
            float x = ze[e];
            s += x; s2 += x*x;
            #pragma unroll
            for (int h = 0; h < H_; ++h)
                acc[h] += x * ww[h*CZ_ + c4*4 + e];   // uniform address -> s_load
        }
    }
    float m = s * (1.f/CZ_);
    float var = s2 * (1.f/CZ_) - m*m;
    float r = rsqrtf(var + EPS_);
    #pragma unroll
    for (int h = 0; h < H_; ++h)
        bias[(size_t)h*LL_ + p] = r*(acc[h] - m*sumww[h]) + bb[h];
}

// ---------------- LayerNorm(s) ----------------
__global__ void sln_kernel(const float* __restrict__ s, const float* __restrict__ w,
                           const float* __restrict__ b, float* __restrict__ sn) {
    int row = blockIdx.x;
    int lane = threadIdx.x;   // 64
    float x[6];
    float sum = 0.f, sum2 = 0.f;
    #pragma unroll
    for (int j = 0; j < 6; ++j) {
        x[j] = s[row*CS_ + lane + j*64];
        sum += x[j]; sum2 += x[j]*x[j];
    }
    #pragma unroll
    for (int off = 32; off; off >>= 1) {
        sum  += __shfl_xor(sum,  off);
        sum2 += __shfl_xor(sum2, off);
    }
    float m = sum * (1.f/CS_);
    float r = rsqrtf(sum2*(1.f/CS_) - m*m + EPS_);
    #pragma unroll
    for (int j = 0; j < 6; ++j) {
        int c = lane + j*64;
        sn[row*CS_ + c] = (x[j]-m)*r*w[c] + b[c];
    }
}

// ---------------- QKVG projections: C[768,1536] = sn * [wq;wk;wv;wg]^T ----------------
// 64x64 tile, BK=16, 256 threads, 4x4 microtile. Fused epilogues.
__global__ __launch_bounds__(256) void qkvg_kernel(const float* __restrict__ sn,
        const float* __restrict__ wq, const float* __restrict__ wk,
        const float* __restrict__ wv, const float* __restrict__ wg,
        const float* __restrict__ bg,
        float* __restrict__ qb, float* __restrict__ kb,
        float* __restrict__ vb, float* __restrict__ gb) {
    __shared__ float As[16][68];
    __shared__ float Bs[16][68];
    int m0 = blockIdx.x * 64;
    int n0 = blockIdx.y * 64;            // 0..1472
    int sel = n0 / 384;                  // 0=q 1=k 2=v 3=g
    const float* W = (sel==0) ? wq : (sel==1) ? wk : (sel==2) ? wv : wg;
    float* C       = (sel==0) ? qb : (sel==1) ? kb : (sel==2) ? vb : gb;
    int ncol0 = n0 - sel*384;

    int t  = threadIdx.x;
    int lr = t >> 2;            // 0..63
    int lc = (t & 3) * 4;       // 0,4,8,12
    int ty = t >> 4;            // 0..15
    int tx = t & 15;            // 0..15

    float acc[4][4] = {};
    for (int k0 = 0; k0 < CS_; k0 += 16) {
        float4 av = *(const float4*)(sn + (size_t)(m0 + lr)*CS_ + k0 + lc);
        float4 bv = *(const float4*)(W  + (size_t)(ncol0 + lr)*CS_ + k0 + lc);
        As[lc+0][lr] = av.x; As[lc+1][lr] = av.y; As[lc+2][lr] = av.z; As[lc+3][lr] = av.w;
        Bs[lc+0][lr] = bv.x; Bs[lc+1][lr] = bv.y; Bs[lc+2][lr] = bv.z; Bs[lc+3][lr] = bv.w;
        __syncthreads();
        #pragma unroll
        for (int kk = 0; kk < 16; ++kk) {
            float4 a4 = *(const float4*)&As[kk][ty*4];
            float4 b4 = *(const float4*)&Bs[kk][tx*4];
            float a[4] = {a4.x,a4.y,a4.z,a4.w};
            float bb_[4] = {b4.x,b4.y,b4.z,b4.w};
            #pragma unroll
            for (int i = 0; i < 4; ++i)
                #pragma unroll
                for (int j = 0; j < 4; ++j)
                    acc[i][j] += a[i]*bb_[j];
        }
        __syncthreads();
    }
    #pragma unroll
    for (int i = 0; i < 4; ++i) {
        int row = m0 + ty*4 + i;
        #pragma unroll
        for (int j = 0; j < 4; ++j) {
            int col = ncol0 + tx*4 + j;
            float v = acc[i][j];
            if (sel == 0) v *= 0.17677669529663687f;          // CH^-0.5
            if (sel == 3) v = 1.f/(1.f + __expf(-(v + bg[col])));
            C[(size_t)row*CS_ + col] = v;
        }
    }
}

// ---------------- attention: per (head, 16-row q tile) ----------------
#define QT_ 16
__global__ __launch_bounds__(256) void attn_kernel(const float* __restrict__ qb,
        const float* __restrict__ kb, const float* __restrict__ vb,
        const float* __restrict__ gb, const float* __restrict__ bias,
        float* __restrict__ og) {
    __shared__ float Sm[QT_][772];     // scores, padded stride
    __shared__ float KVt[CH_][68];     // K or V tile, transposed [c][k]
    int h  = blockIdx.x;
    int q0 = blockIdx.y * QT_;
    int t  = threadIdx.x;

    int tq1 = t >> 4;   // 0..15 (q row)
    int tk1 = t & 15;   // 0..15 (k quad)

    // own q row in registers
    float qreg[CH_];
    {
        const float4* qsrc = (const float4*)(qb + (size_t)(q0 + tq1)*CS_ + h*CH_);
        #pragma unroll
        for (int i = 0; i < 8; ++i) {
            float4 qv = qsrc[i];
            qreg[i*4+0]=qv.x; qreg[i*4+1]=qv.y; qreg[i*4+2]=qv.z; qreg[i*4+3]=qv.w;
        }
    }

    // ---- phase 1: S = qK^T + bias ----
    for (int kt = 0; kt < L_; kt += 64) {
        #pragma unroll
        for (int r2 = 0; r2 < 2; ++r2) {
            int row = (t >> 3) + 32*r2;        // 0..63
            int c   = (t & 7) * 4;             // 0..28
            float4 kv = *(const float4*)(kb + (size_t)(kt+row)*CS_ + h*CH_ + c);
            KVt[c+0][row]=kv.x; KVt[c+1][row]=kv.y; KVt[c+2][row]=kv.z; KVt[c+3][row]=kv.w;
        }
        __syncthreads();
        float sacc[4] = {0,0,0,0};
        #pragma unroll
        for (int c = 0; c < CH_; ++c) {
            float4 kv4 = *(const float4*)&KVt[c][tk1*4];
            sacc[0] += qreg[c]*kv4.x;
            sacc[1] += qreg[c]*kv4.y;
            sacc[2] += qreg[c]*kv4.z;
            sacc[3] += qreg[c]*kv4.w;
        }
        float4 bv = *(const float4*)(bias + (size_t)h*LL_ + (size_t)(q0+tq1)*L_ + kt + tk1*4);
        float4 sv;
        sv.x = sacc[0]+bv.x; sv.y = sacc[1]+bv.y; sv.z = sacc[2]+bv.z; sv.w = sacc[3]+bv.w;
        *(float4*)&Sm[tq1][kt + tk1*4] = sv;
        __syncthreads();
    }

    // ---- phase 2: softmax rows (16 lanes per row) ----
    {
        int qq  = t >> 4;
        int sub = t & 15;
        float mx = -1e30f;
        for (int k = sub; k < L_; k += 16) mx = fmaxf(mx, Sm[qq][k]);
        #pragma unroll
        for (int off = 8; off; off >>= 1) mx = fmaxf(mx, __shfl_xor(mx, off));
        float ssum = 0.f;
        for (int k = sub; k < L_; k += 16) {
            float e = __expf(Sm[qq][k] - mx);
            Sm[qq][k] = e;
            ssum += e;
        }
        #pragma unroll
        for (int off = 8; off; off >>= 1) ssum += __shfl_xor(ssum, off);
        float inv = 1.f/ssum;
        for (int k = sub; k < L_; k += 16) Sm[qq][k] *= inv;
        __syncthreads();
    }

    // ---- phase 3: O = P V, gated store ----
    {
        int tq3 = t >> 4;   // q row
        int tc  = t & 15;   // channel (and +16)
        float o0 = 0.f, o1 = 0.f;
        for (int kt = 0; kt < L_; kt += 64) {
            #pragma unroll
            for (int r2 = 0; r2 < 2; ++r2) {
                int row = (t >> 3) + 32*r2;
                int c   = (t & 7) * 4;
                float4 vv = *(const float4*)(vb + (size_t)(kt+row)*CS_ + h*CH_ + c);
                KVt[c+0][row]=vv.x; KVt[c+1][row]=vv.y; KVt[c+2][row]=vv.z; KVt[c+3][row]=vv.w;
            }
            __syncthreads();
            #pragma unroll
            for (int j4 = 0; j4 < 16; ++j4) {
                float4 pv = *(const float4*)&Sm[tq3][kt + j4*4];
                float4 va = *(const float4*)&KVt[tc][j4*4];
                float4 vbv = *(const float4*)&KVt[tc+16][j4*4];
                o0 += pv.x*va.x + pv.y*va.y + pv.z*va.z + pv.w*va.w;
                o1 += pv.x*vbv.x + pv.y*vbv.y + pv.z*vbv.z + pv.w*vbv.w;
            }
            __syncthreads();
        }
        int row = q0 + tq3;
        int c   = h*CH_ + tc;
        og[(size_t)row*CS_ + c]      = o0 * gb[(size_t)row*CS_ + c];
        og[(size_t)row*CS_ + c + 16] = o1 * gb[(size_t)row*CS_ + c + 16];
    }
}

// ---------------- out projection: out = og * w_o^T + b_o ----------------
__global__ __launch_bounds__(256) void outproj_kernel(const float* __restrict__ og,
        const float* __restrict__ wo, const float* __restrict__ bo,
        float* __restrict__ out) {
    __shared__ float As[16][68];
    __shared__ float Bs[16][68];
    int m0 = blockIdx.x * 64;
    int n0 = blockIdx.y * 64;
    int t  = threadIdx.x;
    int lr = t >> 2;
    int lc = (t & 3) * 4;
    int ty = t >> 4;
    int tx = t & 15;
    float acc[4][4] = {};
    for (int k0 = 0; k0 < CS_; k0 += 16) {
        float4 av = *(const float4*)(og + (size_t)(m0 + lr)*CS_ + k0 + lc);
        float4 bv = *(const float4*)(wo + (size_t)(n0 + lr)*CS_ + k0 + lc);
        As[lc+0][lr] = av.x; As[lc+1][lr] = av.y; As[lc+2][lr] = av.z; As[lc+3][lr] = av.w;
        Bs[lc+0][lr] = bv.x; Bs[lc+1][lr] = bv.y; Bs[lc+2][lr] = bv.z; Bs[lc+3][lr] = bv.w;
        __syncthreads();
        #pragma unroll
        for (int kk = 0; kk < 16; ++kk) {
            float4 a4 = *(const float4*)&As[kk][ty*4];
            float4 b4 = *(const float4*)&Bs[kk][tx*4];
            float a[4] = {a4.x,a4.y,a4.z,a4.w};
            float bb_[4] = {b4.x,b4.y,b4.z,b4.w};
            #pragma unroll
            for (int i = 0; i < 4; ++i)
                #pragma unroll
                for (int j = 0; j < 4; ++j)
                    acc[i][j] += a[i]*bb_[j];
        }
        __syncthreads();
    }
    #pragma unroll
    for (int i = 0; i < 4; ++i) {
        int row = m0 + ty*4 + i;
        #pragma unroll
        for (int j = 0; j < 4; ++j) {
            int col = n0 + tx*4 + j;
            out[(size_t)row*CS_ + col] = acc[i][j] + bo[col];
        }
    }
}

extern "C" void kernel_launch(void* const* d_in, const int* in_sizes, int n_in,
                              void* d_out, int out_size, void* d_ws, size_t ws_size,
                              hipStream_t stream) {
    const float* s      = (const float*)d_in[0];
    const float* z      = (const float*)d_in[1];
    const float* ln_s_w = (const float*)d_in[2];
    const float* ln_s_b = (const float*)d_in[3];
    const float* ln_z_w = (const float*)d_in[4];
    const float* ln_z_b = (const float*)d_in[5];
    const float* w_z    = (const float*)d_in[6];
    const float* w_q    = (const float*)d_in[7];
    const float* w_k    = (const float*)d_in[8];
    const float* w_v    = (const float*)d_in[9];
    const float* w_g    = (const float*)d_in[10];
    const float* b_g    = (const float*)d_in[11];
    const float* w_o    = (const float*)d_in[12];
    const float* b_o    = (const float*)d_in[13];
    float* out = (float*)d_out;

    float* ws    = (float*)d_ws;
    float* bias  = ws;                       // 12*768*768 = 7,077,888
    float* sn    = bias + (size_t)H_*LL_;    // 294,912
    float* qb    = sn + (size_t)L_*CS_;
    float* kb    = qb + (size_t)L_*CS_;
    float* vb    = kb + (size_t)L_*CS_;
    float* gb    = vb + (size_t)L_*CS_;
    float* og    = gb + (size_t)L_*CS_;
    float* ww    = og + (size_t)L_*CS_;      // 1536
    float* sumww = ww + (size_t)H_*CZ_;      // 16
    float* bbuf  = sumww + 16;

    hipLaunchKernelGGL(prep_kernel, dim3(1), dim3(64), 0, stream,
                       ln_z_w, ln_z_b, w_z, ww, sumww, bbuf);
    hipLaunchKernelGGL(bias_kernel, dim3(LL_/256), dim3(256), 0, stream,
                       z, ww, sumww, bbuf, bias);
    hipLaunchKernelGGL(sln_kernel, dim3(L_), dim3(64), 0, stream,
                       s, ln_s_w, ln_s_b, sn);
    hipLaunchKernelGGL(qkvg_kernel, dim3(L_/64, 1536/64), dim3(256), 0, stream,
                       sn, w_q, w_k, w_v, w_g, b_g, qb, kb, vb, gb);
    hipLaunchKernelGGL(attn_kernel, dim3(H_, L_/QT_), dim3(256), 0, stream,
                       qb, kb, vb, gb, bias, og);
    hipLaunchKernelGGL(outproj_kernel, dim3(L_/64, CS_/64), dim3(256), 0, stream,
                       og, w_o, b_o, out);
}